// Round 1
// baseline (308.549 us; speedup 1.0000x reference)
//
#include <hip/hip_runtime.h>
#include <hip/hip_bf16.h>
#include <stdint.h>

#define DEV __device__ __forceinline__

typedef unsigned short u16;
typedef __attribute__((ext_vector_type(8))) short bf16x8;   // 8 bf16 (4 VGPRs) MFMA A/B frag
typedef __attribute__((ext_vector_type(4))) float f32x4;    // MFMA C/D frag

DEV u16 f2bf(float f) {
  union { float f; uint32_t u; } v; v.f = f;
  uint32_t r = v.u + 0x7FFFu + ((v.u >> 16) & 1u);  // round-to-nearest-even
  return (u16)(r >> 16);
}

DEV float sigmoid_fast(float x) {
  float e = __builtin_amdgcn_exp2f(x * -1.44269504088896340736f);
  return __builtin_amdgcn_rcpf(1.0f + e);
}

// ---------------- f32 -> bf16 conversion (x, Wq, Wv) ----------------
__global__ void conv_kernel(const float* __restrict__ x,
                            const float* __restrict__ Wq,
                            const float* __restrict__ Wv,
                            u16* __restrict__ xb,
                            u16* __restrict__ wqb,
                            u16* __restrict__ wvb) {
  const int NX4 = (16384 * 512) / 4;
  const int NW4 = (512 * 512) / 4;
  int i = blockIdx.x * blockDim.x + threadIdx.x;
  const float4* src; u16* dst; int off;
  if (i < NX4)            { src = (const float4*)x;  dst = xb;  off = i; }
  else if (i < NX4 + NW4) { src = (const float4*)Wq; dst = wqb; off = i - NX4; }
  else                    { src = (const float4*)Wv; dst = wvb; off = i - NX4 - NW4; }
  float4 f = src[off];
  ushort4 o = make_ushort4(f2bf(f.x), f2bf(f.y), f2bf(f.z), f2bf(f.w));
  ((ushort4*)dst)[off] = o;
}

// ---------------- generic 128x128x(BK=64) NT GEMM, bf16 in, MFMA ----------------
// C[m][n] = sum_k A[m][k] * B[n][k]  (both row-major with K inner = NT)
// EPI: 0 = +bias[col] -> bf16 | 1 = +bias[row] -> bf16 | 2 = sigmoid(x/sqrt(512)) -> bf16 | 3 = f32 out
template <int EPI>
__global__ __launch_bounds__(256, 2)
void gemm_nt(const u16* __restrict__ A, int lda, long sAz,
             const u16* __restrict__ B, int ldb, long sBz,
             void* __restrict__ Cv, int ldc, long sCz,
             const float* __restrict__ bias, int K) {
  __shared__ u16 Alds[128 * 64];   // 16 KB, row-major [128][64]
  __shared__ u16 Blds[128 * 64];   // 16 KB

  const int tid  = threadIdx.x;
  const int lane = tid & 63;
  const int w    = tid >> 6;        // wave 0..3
  const int wr   = w >> 1, wc = w & 1;
  const int bn = blockIdx.x, bm = blockIdx.y, z = blockIdx.z;

  A += (long)z * sAz;
  B += (long)z * sBz;

  const int lrow = lane & 15;           // frag row (A) / col (B)
  const int lk   = (lane >> 4) << 3;    // frag k-base (contiguous 8 per lane)

  // staging geometry: each global_load_lds = 1 KB = 8 rows x 64 cols(bf16); 4 chunks/wave
  const int srow = lane >> 3;           // 0..7 within chunk
  const int scol = (lane & 7) << 3;     // element col 0,8,..,56

  const u16* gA = A + (long)(bm * 128 + w * 32 + srow) * lda + scol;
  const u16* gB = B + (long)(bn * 128 + w * 32 + srow) * ldb + scol;

  f32x4 acc[4][4] = {};

  const int nk = K >> 6;
  for (int kt = 0; kt < nk; ++kt) {
    const u16* pa = gA + kt * 64;
    const u16* pb = gB + kt * 64;
#pragma unroll
    for (int c = 0; c < 4; ++c) {
      __builtin_amdgcn_global_load_lds(
          (const __attribute__((address_space(1))) uint32_t*)(pa + (long)c * 8 * lda),
          (__attribute__((address_space(3))) uint32_t*)(&Alds[(w * 32 + c * 8) * 64]), 16, 0, 0);
      __builtin_amdgcn_global_load_lds(
          (const __attribute__((address_space(1))) uint32_t*)(pb + (long)c * 8 * ldb),
          (__attribute__((address_space(3))) uint32_t*)(&Blds[(w * 32 + c * 8) * 64]), 16, 0, 0);
    }
    __syncthreads();  // drains vmcnt before barrier (compiler-inserted)

#pragma unroll
    for (int ks = 0; ks < 2; ++ks) {
      bf16x8 af[4], bfr[4];
#pragma unroll
      for (int t = 0; t < 4; ++t) {
        af[t]  = *(const bf16x8*)&Alds[(wr * 64 + t * 16 + lrow) * 64 + ks * 32 + lk];
        bfr[t] = *(const bf16x8*)&Blds[(wc * 64 + t * 16 + lrow) * 64 + ks * 32 + lk];
      }
#pragma unroll
      for (int mt = 0; mt < 4; ++mt)
#pragma unroll
        for (int nt = 0; nt < 4; ++nt)
          acc[mt][nt] = __builtin_amdgcn_mfma_f32_16x16x32_bf16(af[mt], bfr[nt], acc[mt][nt], 0, 0, 0);
    }
    __syncthreads();
  }

  // epilogue: C/D layout col = lane&15, row = (lane>>4)*4 + r  [verified m89/m91]
  const int row0 = bm * 128 + wr * 64;
  const int col0 = bn * 128 + wc * 64;
  const int rsub = (lane >> 4) << 2;

  if (EPI == 3) {
    float* C = (float*)Cv + (long)z * sCz;
#pragma unroll
    for (int mt = 0; mt < 4; ++mt)
#pragma unroll
      for (int nt = 0; nt < 4; ++nt)
#pragma unroll
        for (int r = 0; r < 4; ++r) {
          int row = row0 + mt * 16 + rsub + r;
          int col = col0 + nt * 16 + lrow;
          C[(long)row * ldc + col] = acc[mt][nt][r];
        }
  } else {
    u16* C = (u16*)Cv + (long)z * sCz;
#pragma unroll
    for (int mt = 0; mt < 4; ++mt)
#pragma unroll
      for (int nt = 0; nt < 4; ++nt)
#pragma unroll
        for (int r = 0; r < 4; ++r) {
          int row = row0 + mt * 16 + rsub + r;
          int col = col0 + nt * 16 + lrow;
          float v = acc[mt][nt][r];
          if (EPI == 0) v += bias[col];
          if (EPI == 1) v += bias[row];
          if (EPI == 2) v = sigmoid_fast(v * 0.044194173824159216f);  // 1/sqrt(512)
          C[(long)row * ldc + col] = f2bf(v);
        }
  }
}

// ---------------- launch ----------------
extern "C" void kernel_launch(void* const* d_in, const int* in_sizes, int n_in,
                              void* d_out, int out_size, void* d_ws, size_t ws_size,
                              hipStream_t stream) {
  const float* x  = (const float*)d_in[0];   // [4,4096,512]
  const float* Wq = (const float*)d_in[1];   // [512,512]
  const float* bq = (const float*)d_in[2];   // [512]
  const float* Wv = (const float*)d_in[3];   // [512,512]
  const float* bv = (const float*)d_in[4];   // [512]
  float* out = (float*)d_out;                // [4,4096,512] f32

  // workspace carve (all bf16): total ~113 MB
  u16* xb  = (u16*)d_ws;                       // [16384][512]
  u16* qb  = xb  + (size_t)16384 * 512;        // [16384][512]
  u16* vT  = qb  + (size_t)16384 * 512;        // [512][16384]  (v transposed, per-batch col slices)
  u16* wqb = vT  + (size_t)512 * 16384;        // [512][512]
  u16* wvb = wqb + (size_t)512 * 512;          // [512][512]
  u16* P   = wvb + (size_t)512 * 512;          // [2][4096][4096] bf16, reused per batch-pair

  conv_kernel<<<8704, 256, 0, stream>>>(x, Wq, Wv, xb, wqb, wvb);

  // q[n][e] = sum_d xb[n][d]*Wq[e][d] + bq[e]   (bias per col)
  gemm_nt<0><<<dim3(4, 128, 1), 256, 0, stream>>>(xb, 512, 0, wqb, 512, 0,
                                                  qb, 512, 0, bq, 512);
  // vT[e][n] = sum_d Wv[e][d]*xb[n][d] + bv[e]  (bias per row)
  gemm_nt<1><<<dim3(128, 4, 1), 256, 0, stream>>>(wvb, 512, 0, xb, 512, 0,
                                                  vT, 16384, 0, bv, 512);

  for (int p = 0; p < 2; ++p) {
    const u16* qbp = qb + (size_t)p * 2 * 4096 * 512;
    // P = sigmoid(q q^T / sqrt(512)) for batches 2p, 2p+1  -> bf16 [4096][4096] each
    gemm_nt<2><<<dim3(32, 32, 2), 256, 0, stream>>>(qbp, 512, (long)4096 * 512,
                                                    qbp, 512, (long)4096 * 512,
                                                    P, 4096, (long)4096 * 4096, nullptr, 512);
    // O[n][d] = sum_m P[n][m] * v[m][d] ; B-operand = vT rows d, k = m (NT), f32 out
    gemm_nt<3><<<dim3(4, 32, 2), 256, 0, stream>>>(P, 4096, (long)4096 * 4096,
                                                   vT + (size_t)p * 2 * 4096, 16384, (long)4096,
                                                   out + (size_t)p * 2 * 4096 * 512, 512, (long)4096 * 512,
                                                   nullptr, 4096);
  }
}

// Round 2
// 241.994 us; speedup vs baseline: 1.2750x; 1.2750x over previous
//
#include <hip/hip_runtime.h>
#include <hip/hip_bf16.h>
#include <stdint.h>

#define DEV __device__ __forceinline__

typedef unsigned short u16;
typedef __attribute__((ext_vector_type(8))) short bf16x8;   // 8 bf16 (4 VGPRs) MFMA A/B frag
typedef __attribute__((ext_vector_type(4))) float f32x4;    // MFMA C/D frag

DEV u16 f2bf(float f) {
  union { float f; uint32_t u; } v; v.f = f;
  uint32_t r = v.u + 0x7FFFu + ((v.u >> 16) & 1u);  // round-to-nearest-even
  return (u16)(r >> 16);
}

DEV float sigmoid_fast(float x) {
  float e = __builtin_amdgcn_exp2f(x * -1.44269504088896340736f);
  return __builtin_amdgcn_rcpf(1.0f + e);
}

// ---------------- f32 -> bf16 conversion (x, Wq, Wv) ----------------
__global__ void conv_kernel(const float* __restrict__ x,
                            const float* __restrict__ Wq,
                            const float* __restrict__ Wv,
                            u16* __restrict__ xb,
                            u16* __restrict__ wqb,
                            u16* __restrict__ wvb) {
  const int NX4 = (16384 * 512) / 4;
  const int NW4 = (512 * 512) / 4;
  int i = blockIdx.x * blockDim.x + threadIdx.x;
  const float4* src; u16* dst; int off;
  if (i < NX4)            { src = (const float4*)x;  dst = xb;  off = i; }
  else if (i < NX4 + NW4) { src = (const float4*)Wq; dst = wqb; off = i - NX4; }
  else                    { src = (const float4*)Wv; dst = wvb; off = i - NX4 - NW4; }
  float4 f = src[off];
  ushort4 o = make_ushort4(f2bf(f.x), f2bf(f.y), f2bf(f.z), f2bf(f.w));
  ((ushort4*)dst)[off] = o;
}

// ---------------- generic BMxBN x(BK=64) NT GEMM, bf16 in, MFMA ----------------
// C[m][n] = sum_k A[m][k] * B[n][k]  (both row-major with K inner = NT)
// 4 waves as 2x2; wave tile = (BM/2)x(BN/2); MREP=BM/32 NREP=BN/32 frags.
// LDS XOR-swizzle (T2): linear global_load_lds dest; source col-slot pre-XORed
// with (row&7); frag read applies the same involution. Rule #21: both sides.
// EPI: 0 = +bias[col] -> bf16 | 1 = +bias[row] -> bf16 | 2 = sigmoid(x/sqrt(512)) -> bf16 | 3 = f32 out
template <int EPI, int BM, int BN>
__global__ __launch_bounds__(256, 2)
void gemm_nt(const u16* __restrict__ A, int lda, long sAz,
             const u16* __restrict__ B, int ldb, long sBz,
             void* __restrict__ Cv, int ldc, long sCz,
             const float* __restrict__ bias, int K) {
  constexpr int MREP = BM / 32;
  constexpr int NREP = BN / 32;
  constexpr int CPW  = (BM + BN) / 8 / 4;   // 1KB chunks per wave per K-step
  __shared__ u16 lds[(BM + BN) * 64];

  const int tid  = threadIdx.x;
  const int lane = tid & 63;
  const int w    = tid >> 6;        // wave 0..3
  const int wr   = w >> 1, wc = w & 1;
  const int bn = blockIdx.x, bm = blockIdx.y, z = blockIdx.z;

  A += (long)z * sAz;
  B += (long)z * sBz;

  const int lrow = lane & 15;           // frag row (A) / col (B)
  const int rx   = lane & 7;            // (frag_row & 7) — swizzle key

  // staging geometry: each global_load_lds = 1 KB = 8 rows x 64 cols(bf16)
  const int srow = lane >> 3;                    // 0..7 within chunk
  const int scol = ((lane & 7) ^ srow) << 3;     // pre-swizzled source col slot

  const u16* srcs[CPW];
#pragma unroll
  for (int c = 0; c < CPW; ++c) {
    int row = (w * CPW + c) * 8 + srow;          // row within [A-tile | B-tile]
    srcs[c] = (row < BM)
        ? A + (long)(bm * BM + row) * lda + scol
        : B + (long)(bn * BN + (row - BM)) * ldb + scol;
  }

  const u16* Alds = lds;
  const u16* Blds = lds + BM * 64;

  f32x4 acc[MREP][NREP] = {};

  const int nk = K >> 6;
  for (int kt = 0; kt < nk; ++kt) {
#pragma unroll
    for (int c = 0; c < CPW; ++c) {
      __builtin_amdgcn_global_load_lds(
          (const __attribute__((address_space(1))) uint32_t*)(srcs[c] + kt * 64),
          (__attribute__((address_space(3))) uint32_t*)(&lds[(w * CPW + c) * 512]),
          16, 0, 0);
    }
    __syncthreads();  // compiler drains vmcnt before barrier

#pragma unroll
    for (int ks = 0; ks < 2; ++ks) {
      const int sl = ((ks * 4 + (lane >> 4)) ^ rx) << 3;  // swizzled slot -> elem offset
      bf16x8 af[MREP], bfr[NREP];
#pragma unroll
      for (int t = 0; t < MREP; ++t)
        af[t]  = *(const bf16x8*)&Alds[(wr * (BM / 2) + t * 16 + lrow) * 64 + sl];
#pragma unroll
      for (int t = 0; t < NREP; ++t)
        bfr[t] = *(const bf16x8*)&Blds[(wc * (BN / 2) + t * 16 + lrow) * 64 + sl];
#pragma unroll
      for (int mt = 0; mt < MREP; ++mt)
#pragma unroll
        for (int nt = 0; nt < NREP; ++nt)
          acc[mt][nt] = __builtin_amdgcn_mfma_f32_16x16x32_bf16(af[mt], bfr[nt], acc[mt][nt], 0, 0, 0);
    }
    __syncthreads();
  }

  // epilogue: C/D layout col = lane&15, row = (lane>>4)*4 + r  [verified m89/m91]
  const int row0 = bm * BM + wr * (BM / 2);
  const int col0 = bn * BN + wc * (BN / 2);
  const int rsub = (lane >> 4) << 2;

  if (EPI == 3) {
    float* C = (float*)Cv + (long)z * sCz;
#pragma unroll
    for (int mt = 0; mt < MREP; ++mt)
#pragma unroll
      for (int nt = 0; nt < NREP; ++nt)
#pragma unroll
        for (int r = 0; r < 4; ++r) {
          int row = row0 + mt * 16 + rsub + r;
          int col = col0 + nt * 16 + lrow;
          C[(long)row * ldc + col] = acc[mt][nt][r];
        }
  } else {
    u16* C = (u16*)Cv + (long)z * sCz;
#pragma unroll
    for (int mt = 0; mt < MREP; ++mt)
#pragma unroll
      for (int nt = 0; nt < NREP; ++nt)
#pragma unroll
        for (int r = 0; r < 4; ++r) {
          int row = row0 + mt * 16 + rsub + r;
          int col = col0 + nt * 16 + lrow;
          float v = acc[mt][nt][r];
          if (EPI == 0) v += bias[col];
          if (EPI == 1) v += bias[row];
          if (EPI == 2) v = sigmoid_fast(v * 0.044194173824159216f);  // 1/sqrt(512)
          C[(long)row * ldc + col] = f2bf(v);
        }
  }
}

// ---------------- launch ----------------
extern "C" void kernel_launch(void* const* d_in, const int* in_sizes, int n_in,
                              void* d_out, int out_size, void* d_ws, size_t ws_size,
                              hipStream_t stream) {
  const float* x  = (const float*)d_in[0];   // [4,4096,512]
  const float* Wq = (const float*)d_in[1];   // [512,512]
  const float* bq = (const float*)d_in[2];   // [512]
  const float* Wv = (const float*)d_in[3];   // [512,512]
  const float* bv = (const float*)d_in[4];   // [512]
  float* out = (float*)d_out;                // [4,4096,512] f32

  // workspace carve (all bf16): total ~113 MB
  u16* xb  = (u16*)d_ws;                       // [16384][512]
  u16* qb  = xb  + (size_t)16384 * 512;        // [16384][512]
  u16* vT  = qb  + (size_t)16384 * 512;        // [512][16384]  (v transposed, per-batch col slices)
  u16* wqb = vT  + (size_t)512 * 16384;        // [512][512]
  u16* wvb = wqb + (size_t)512 * 512;          // [512][512]
  u16* P   = wvb + (size_t)512 * 512;          // [2][4096][4096] bf16, reused per batch-pair

  conv_kernel<<<8704, 256, 0, stream>>>(x, Wq, Wv, xb, wqb, wvb);

  // q[n][e] = sum_d xb[n][d]*Wq[e][d] + bq[e]   (bias per col)
  gemm_nt<0, 128, 128><<<dim3(4, 128, 1), 256, 0, stream>>>(xb, 512, 0, wqb, 512, 0,
                                                            qb, 512, 0, bq, 512);
  // vT[e][n] = sum_d Wv[e][d]*xb[n][d] + bv[e]  (bias per row)
  gemm_nt<1, 128, 128><<<dim3(128, 4, 1), 256, 0, stream>>>(wvb, 512, 0, xb, 512, 0,
                                                            vT, 16384, 0, bv, 512);

  for (int p = 0; p < 2; ++p) {
    const u16* qbp = qb + (size_t)p * 2 * 4096 * 512;
    // P = sigmoid(q q^T / sqrt(512)) for batches 2p, 2p+1  -> bf16 [4096][4096] each
    gemm_nt<2, 128, 128><<<dim3(32, 32, 2), 256, 0, stream>>>(qbp, 512, (long)4096 * 512,
                                                              qbp, 512, (long)4096 * 512,
                                                              P, 4096, (long)4096 * 4096, nullptr, 512);
    // O[n][d] = sum_m P[n][m] * v[m][d] ; B-operand = vT rows d, k = m (NT), f32 out
    // 64x128 tile -> grid 4x64x2 = 512 blocks = 2 blocks/CU (was 256 = 1/CU, latency-bound)
    gemm_nt<3, 64, 128><<<dim3(4, 64, 2), 256, 0, stream>>>(P, 4096, (long)4096 * 4096,
                                                            vT + (size_t)p * 2 * 4096, 16384, (long)4096,
                                                            out + (size_t)p * 2 * 4096 * 512, 512, (long)4096 * 512,
                                                            nullptr, 4096);
  }
}

// Round 3
// 205.458 us; speedup vs baseline: 1.5018x; 1.1778x over previous
//
#include <hip/hip_runtime.h>
#include <hip/hip_bf16.h>
#include <stdint.h>

#define DEV __device__ __forceinline__

typedef unsigned short u16;
typedef __attribute__((ext_vector_type(8))) short bf16x8;   // 8 bf16 (4 VGPRs) MFMA A/B frag
typedef __attribute__((ext_vector_type(4))) float f32x4;    // MFMA C/D frag

DEV u16 f2bf(float f) {
  union { float f; uint32_t u; } v; v.f = f;
  uint32_t r = v.u + 0x7FFFu + ((v.u >> 16) & 1u);  // round-to-nearest-even
  return (u16)(r >> 16);
}

DEV float sigmoid_fast(float x) {
  float e = __builtin_amdgcn_exp2f(x * -1.44269504088896340736f);
  return __builtin_amdgcn_rcpf(1.0f + e);
}

// ---------------- f32 -> bf16 conversion (x, Wq, Wv) ----------------
__global__ void conv_kernel(const float* __restrict__ x,
                            const float* __restrict__ Wq,
                            const float* __restrict__ Wv,
                            u16* __restrict__ xb,
                            u16* __restrict__ wqb,
                            u16* __restrict__ wvb) {
  const int NX4 = (16384 * 512) / 4;
  const int NW4 = (512 * 512) / 4;
  int i = blockIdx.x * blockDim.x + threadIdx.x;
  const float4* src; u16* dst; int off;
  if (i < NX4)            { src = (const float4*)x;  dst = xb;  off = i; }
  else if (i < NX4 + NW4) { src = (const float4*)Wq; dst = wqb; off = i - NX4; }
  else                    { src = (const float4*)Wv; dst = wvb; off = i - NX4 - NW4; }
  float4 f = src[off];
  ushort4 o = make_ushort4(f2bf(f.x), f2bf(f.y), f2bf(f.z), f2bf(f.w));
  ((ushort4*)dst)[off] = o;
}

// ---------------- generic BMxBN x(BK=64) NT GEMM, bf16 in, MFMA ----------------
// C[m][n] = sum_k A[m][k] * B[n][k]  (both row-major with K inner = NT)
// Flat grid = NBN*NBM*NZ blocks; XCD-chunked bijective swizzle (T1, m204):
//   swz = (id%8)*(nwg/8) + id/8, decoded bn-fastest so one bm-stripe's bn-blocks
//   share an XCD (A-panel fetched once per XCD). nwg must be divisible by 8.
// 4 waves as 2x2; wave tile = (BM/2)x(BN/2); MREP=BM/32 NREP=BN/32 frags.
// LDS XOR-swizzle (T2): linear global_load_lds dest; source col-slot pre-XORed
// with (row&7); frag read applies the same involution. Rule #21: both sides.
// EPI: 0 = +bias[col] -> bf16 | 1 = +bias[row] -> bf16 | 2 = sigmoid(x/sqrt(512)) -> bf16 | 3 = f32 out
template <int EPI, int BM, int BN, int NBN, int NBM>
__global__ __launch_bounds__(256, 2)
void gemm_nt(const u16* __restrict__ A, int lda, long sAz,
             const u16* __restrict__ B, int ldb, long sBz,
             void* __restrict__ Cv, int ldc, long sCz,
             const float* __restrict__ bias, int K) {
  constexpr int MREP = BM / 32;
  constexpr int NREP = BN / 32;
  constexpr int CPW  = (BM + BN) / 8 / 4;   // 1KB chunks per wave per K-step
  __shared__ u16 lds[(BM + BN) * 64];

  const int tid  = threadIdx.x;
  const int lane = tid & 63;
  const int w    = tid >> 6;        // wave 0..3
  const int wr   = w >> 1, wc = w & 1;

  // XCD-chunked swizzle (grid is flat, nwg % 8 == 0)
  const int nwg = NBN * NBM * ((int)gridDim.x / (NBN * NBM));
  const int id  = blockIdx.x;
  const int swz = (id & 7) * (nwg >> 3) + (id >> 3);
  const int bn  = swz % NBN;
  const int t0  = swz / NBN;
  const int bm  = t0 % NBM;
  const int z   = t0 / NBM;

  A += (long)z * sAz;
  B += (long)z * sBz;

  const int lrow = lane & 15;           // frag row (A) / col (B)
  const int rx   = lane & 7;            // (frag_row & 7) — swizzle key

  // staging geometry: each global_load_lds = 1 KB = 8 rows x 64 cols(bf16)
  const int srow = lane >> 3;                    // 0..7 within chunk
  const int scol = ((lane & 7) ^ srow) << 3;     // pre-swizzled source col slot

  const u16* srcs[CPW];
#pragma unroll
  for (int c = 0; c < CPW; ++c) {
    int row = (w * CPW + c) * 8 + srow;          // row within [A-tile | B-tile]
    srcs[c] = (row < BM)
        ? A + (long)(bm * BM + row) * lda + scol
        : B + (long)(bn * BN + (row - BM)) * ldb + scol;
  }

  const u16* Alds = lds;
  const u16* Blds = lds + BM * 64;

  f32x4 acc[MREP][NREP] = {};

  const int nk = K >> 6;
  for (int kt = 0; kt < nk; ++kt) {
#pragma unroll
    for (int c = 0; c < CPW; ++c) {
      __builtin_amdgcn_global_load_lds(
          (const __attribute__((address_space(1))) uint32_t*)(srcs[c] + kt * 64),
          (__attribute__((address_space(3))) uint32_t*)(&lds[(w * CPW + c) * 512]),
          16, 0, 0);
    }
    __syncthreads();  // compiler drains vmcnt before barrier

#pragma unroll
    for (int ks = 0; ks < 2; ++ks) {
      const int sl = ((ks * 4 + (lane >> 4)) ^ rx) << 3;  // swizzled slot -> elem offset
      bf16x8 af[MREP], bfr[NREP];
#pragma unroll
      for (int t = 0; t < MREP; ++t)
        af[t]  = *(const bf16x8*)&Alds[(wr * (BM / 2) + t * 16 + lrow) * 64 + sl];
#pragma unroll
      for (int t = 0; t < NREP; ++t)
        bfr[t] = *(const bf16x8*)&Blds[(wc * (BN / 2) + t * 16 + lrow) * 64 + sl];
#pragma unroll
      for (int mt = 0; mt < MREP; ++mt)
#pragma unroll
        for (int nt = 0; nt < NREP; ++nt)
          acc[mt][nt] = __builtin_amdgcn_mfma_f32_16x16x32_bf16(af[mt], bfr[nt], acc[mt][nt], 0, 0, 0);
    }
    __syncthreads();
  }

  // epilogue: C/D layout col = lane&15, row = (lane>>4)*4 + r  [verified m89/m91]
  const int row0 = bm * BM + wr * (BM / 2);
  const int col0 = bn * BN + wc * (BN / 2);
  const int rsub = (lane >> 4) << 2;

  if (EPI == 3) {
    float* C = (float*)Cv + (long)z * sCz;
#pragma unroll
    for (int mt = 0; mt < MREP; ++mt)
#pragma unroll
      for (int nt = 0; nt < NREP; ++nt)
#pragma unroll
        for (int r = 0; r < 4; ++r) {
          int row = row0 + mt * 16 + rsub + r;
          int col = col0 + nt * 16 + lrow;
          C[(long)row * ldc + col] = acc[mt][nt][r];
        }
  } else {
    u16* C = (u16*)Cv + (long)z * sCz;
#pragma unroll
    for (int mt = 0; mt < MREP; ++mt)
#pragma unroll
      for (int nt = 0; nt < NREP; ++nt)
#pragma unroll
        for (int r = 0; r < 4; ++r) {
          int row = row0 + mt * 16 + rsub + r;
          int col = col0 + nt * 16 + lrow;
          float v = acc[mt][nt][r];
          if (EPI == 0) v += bias[col];
          if (EPI == 1) v += bias[row];
          if (EPI == 2) v = sigmoid_fast(v * 0.044194173824159216f);  // 1/sqrt(512)
          C[(long)row * ldc + col] = f2bf(v);
        }
  }
}

// ---------------- launch ----------------
extern "C" void kernel_launch(void* const* d_in, const int* in_sizes, int n_in,
                              void* d_out, int out_size, void* d_ws, size_t ws_size,
                              hipStream_t stream) {
  const float* x  = (const float*)d_in[0];   // [4,4096,512]
  const float* Wq = (const float*)d_in[1];   // [512,512]
  const float* bq = (const float*)d_in[2];   // [512]
  const float* Wv = (const float*)d_in[3];   // [512,512]
  const float* bv = (const float*)d_in[4];   // [512]
  float* out = (float*)d_out;                // [4,4096,512] f32

  // workspace carve (all bf16)
  u16* xb  = (u16*)d_ws;                       // [16384][512]
  u16* qb  = xb  + (size_t)16384 * 512;        // [16384][512]
  u16* vT  = qb  + (size_t)16384 * 512;        // [512][16384]  (v transposed; batch col slices)
  u16* wqb = vT  + (size_t)512 * 16384;        // [512][512]
  u16* wvb = wqb + (size_t)512 * 512;          // [512][512]
  u16* P   = wvb + (size_t)512 * 512;          // [4 or 2][4096][4096] bf16

  const size_t base_elems = (size_t)16384 * 512 * 3 + (size_t)512 * 512 * 2;
  const size_t need_all4  = (base_elems + (size_t)4 * 4096 * 4096) * sizeof(u16);
  const bool all4 = ws_size >= need_all4;

  conv_kernel<<<8704, 256, 0, stream>>>(x, Wq, Wv, xb, wqb, wvb);

  // q[n][e] = sum_d xb[n][d]*Wq[e][d] + bq[e]   (bias per col)
  gemm_nt<0, 128, 128, 4, 128><<<512, 256, 0, stream>>>(xb, 512, 0, wqb, 512, 0,
                                                        qb, 512, 0, bq, 512);
  // vT[e][n] = sum_d Wv[e][d]*xb[n][d] + bv[e]  (bias per row)
  gemm_nt<1, 128, 128, 128, 4><<<512, 256, 0, stream>>>(wvb, 512, 0, xb, 512, 0,
                                                        vT, 16384, 0, bv, 512);

  if (all4) {
    // P = sigmoid(q q^T / sqrt(512)) for all 4 batches -> bf16 [4][4096][4096]
    gemm_nt<2, 128, 128, 32, 32><<<4096, 256, 0, stream>>>(
        qb, 512, (long)4096 * 512, qb, 512, (long)4096 * 512,
        P, 4096, (long)4096 * 4096, nullptr, 512);
    // O[n][d] = sum_m P[n][m] * v[m][d]; B-panel = vT rows (d), k = m (NT), f32 out
    // 128x128 tile, 512 blocks = 2 blocks/CU
    gemm_nt<3, 128, 128, 4, 32><<<512, 256, 0, stream>>>(
        P, 4096, (long)4096 * 4096, vT, 16384, (long)4096,
        out, 512, (long)4096 * 512, nullptr, 4096);
  } else {
    for (int p = 0; p < 2; ++p) {
      const u16* qbp = qb + (size_t)p * 2 * 4096 * 512;
      gemm_nt<2, 128, 128, 32, 32><<<2048, 256, 0, stream>>>(
          qbp, 512, (long)4096 * 512, qbp, 512, (long)4096 * 512,
          P, 4096, (long)4096 * 4096, nullptr, 512);
      gemm_nt<3, 64, 128, 4, 64><<<512, 256, 0, stream>>>(
          P, 4096, (long)4096 * 4096, vT + (size_t)p * 2 * 4096, 16384, (long)4096,
          out + (size_t)p * 2 * 4096 * 512, 512, (long)4096 * 512, nullptr, 4096);
    }
  }
}

// Round 4
// 184.137 us; speedup vs baseline: 1.6757x; 1.1158x over previous
//
#include <hip/hip_runtime.h>
#include <hip/hip_bf16.h>
#include <stdint.h>

#define DEV __device__ __forceinline__

typedef unsigned short u16;
typedef __attribute__((ext_vector_type(8))) short bf16x8;   // 8 bf16 (4 VGPRs) MFMA A/B frag
typedef __attribute__((ext_vector_type(4))) float f32x4;    // MFMA C/D frag

DEV u16 bf(float v) {
  __hip_bfloat16 h = __float2bfloat16(v);       // compiler emits good cvt (m240)
  union { __hip_bfloat16 h; u16 u; } x; x.h = h;
  return x.u;
}

// sigmoid(v/sqrt(512)) = 1/(1+exp2(v * -log2(e)/sqrt(512)))
DEV float sigmoid_s(float v) {
  float e = __builtin_amdgcn_exp2f(v * -0.0637587143f);
  return __builtin_amdgcn_rcpf(1.0f + e);
}

// ---------------- f32 -> bf16 conversion (x, Wq, Wv) ----------------
__global__ void conv_kernel(const float* __restrict__ x,
                            const float* __restrict__ Wq,
                            const float* __restrict__ Wv,
                            u16* __restrict__ xb,
                            u16* __restrict__ wqb,
                            u16* __restrict__ wvb) {
  const int NX4 = (16384 * 512) / 4;
  const int NW4 = (512 * 512) / 4;
  int i = blockIdx.x * blockDim.x + threadIdx.x;
  const float4* src; u16* dst; int off;
  if (i < NX4)            { src = (const float4*)x;  dst = xb;  off = i; }
  else if (i < NX4 + NW4) { src = (const float4*)Wq; dst = wqb; off = i - NX4; }
  else                    { src = (const float4*)Wv; dst = wvb; off = i - NX4 - NW4; }
  float4 f = src[off];
  ushort4 o = make_ushort4(bf(f.x), bf(f.y), bf(f.z), bf(f.w));
  ((ushort4*)dst)[off] = o;
}

// ---------------- generic BMxBN x(BK=64) NT GEMM, bf16 in, MFMA ----------------
// C[m][n] = sum_k A[m][k] * B[n][k]  (both row-major with K inner = NT)
// Flat grid; XCD-chunked bijective swizzle (T1, m204), bn-fastest decode.
// LDS XOR-swizzle (T2): linear global_load_lds dest; source col-slot pre-XORed
// with (row&7); frag read applies the same involution (rule #21: both sides).
// EPI: 0 = +bias[col] -> bf16 | 1 = +bias[row] -> bf16 | 3 = f32 out
template <int EPI, int BM, int BN, int NBN, int NBM>
__global__ __launch_bounds__(256, 2)
void gemm_nt(const u16* __restrict__ A, int lda, long sAz,
             const u16* __restrict__ B, int ldb, long sBz,
             void* __restrict__ Cv, int ldc, long sCz,
             const float* __restrict__ bias, int K) {
  constexpr int MREP = BM / 32;
  constexpr int NREP = BN / 32;
  constexpr int CPW  = (BM + BN) / 8 / 4;   // 1KB chunks per wave per K-step
  __shared__ u16 lds[(BM + BN) * 64];

  const int tid  = threadIdx.x;
  const int lane = tid & 63;
  const int w    = tid >> 6;        // wave 0..3
  const int wr   = w >> 1, wc = w & 1;

  const int nwg = (int)gridDim.x;   // divisible by 8
  const int id  = blockIdx.x;
  const int swz = (id & 7) * (nwg >> 3) + (id >> 3);
  const int bn  = swz % NBN;
  const int t0  = swz / NBN;
  const int bm  = t0 % NBM;
  const int z   = t0 / NBM;

  A += (long)z * sAz;
  B += (long)z * sBz;

  const int lrow = lane & 15;           // frag row (A) / col (B)
  const int rx   = lane & 7;            // swizzle key

  const int srow = lane >> 3;                    // 0..7 within 1KB chunk
  const int scol = ((lane & 7) ^ srow) << 3;     // pre-swizzled source col slot

  const u16* srcs[CPW];
#pragma unroll
  for (int c = 0; c < CPW; ++c) {
    int row = (w * CPW + c) * 8 + srow;          // row within [A-tile | B-tile]
    srcs[c] = (row < BM)
        ? A + (long)(bm * BM + row) * lda + scol
        : B + (long)(bn * BN + (row - BM)) * ldb + scol;
  }

  const u16* Alds = lds;
  const u16* Blds = lds + BM * 64;

  f32x4 acc[MREP][NREP] = {};

  const int nk = K >> 6;
  for (int kt = 0; kt < nk; ++kt) {
#pragma unroll
    for (int c = 0; c < CPW; ++c) {
      __builtin_amdgcn_global_load_lds(
          (const __attribute__((address_space(1))) uint32_t*)(srcs[c] + kt * 64),
          (__attribute__((address_space(3))) uint32_t*)(&lds[(w * CPW + c) * 512]),
          16, 0, 0);
    }
    __syncthreads();

#pragma unroll
    for (int ks = 0; ks < 2; ++ks) {
      const int sl = ((ks * 4 + (lane >> 4)) ^ rx) << 3;
      bf16x8 af[MREP], bfr[NREP];
#pragma unroll
      for (int t = 0; t < MREP; ++t)
        af[t]  = *(const bf16x8*)&Alds[(wr * (BM / 2) + t * 16 + lrow) * 64 + sl];
#pragma unroll
      for (int t = 0; t < NREP; ++t)
        bfr[t] = *(const bf16x8*)&Blds[(wc * (BN / 2) + t * 16 + lrow) * 64 + sl];
#pragma unroll
      for (int mt = 0; mt < MREP; ++mt)
#pragma unroll
        for (int nt = 0; nt < NREP; ++nt)
          acc[mt][nt] = __builtin_amdgcn_mfma_f32_16x16x32_bf16(af[mt], bfr[nt], acc[mt][nt], 0, 0, 0);
    }
    __syncthreads();
  }

  // epilogue: C/D layout col = lane&15, row = (lane>>4)*4 + r  [verified m89/m91]
  const int row0 = bm * BM + wr * (BM / 2);
  const int col0 = bn * BN + wc * (BN / 2);
  const int rsub = (lane >> 4) << 2;

  if (EPI == 3) {
    float* C = (float*)Cv + (long)z * sCz;
#pragma unroll
    for (int mt = 0; mt < MREP; ++mt)
#pragma unroll
      for (int nt = 0; nt < NREP; ++nt)
#pragma unroll
        for (int r = 0; r < 4; ++r)
          C[(long)(row0 + mt * 16 + rsub + r) * ldc + col0 + nt * 16 + lrow] = acc[mt][nt][r];
  } else {
    u16* C = (u16*)Cv + (long)z * sCz;
#pragma unroll
    for (int mt = 0; mt < MREP; ++mt)
#pragma unroll
      for (int nt = 0; nt < NREP; ++nt)
#pragma unroll
        for (int r = 0; r < 4; ++r) {
          int row = row0 + mt * 16 + rsub + r;
          int col = col0 + nt * 16 + lrow;
          float v = acc[mt][nt][r];
          if (EPI == 0) v += bias[col];
          if (EPI == 1) v += bias[row];
          C[(long)row * ldc + col] = bf(v);
        }
  }
}

// ---------------- symmetric sigmoid(QQ^T) GEMM: only bn>=bm tiles ----------------
// Grid = Z * 528 flat (XCD-swizzled). Off-diagonal blocks also store the
// transposed tile: each frag's 4 consecutive-row values become 4 consecutive
// columns of one row in P^T -> one ushort4 (8B) packed store per frag.
template <int NB>   // tiles per dim; BM=BN=128; TRI = NB*(NB+1)/2
__global__ __launch_bounds__(256, 2)
void gemm_sym_sig(const u16* __restrict__ Q, int ldq, long sQz,
                  u16* __restrict__ P, int ldp, long sPz, int K) {
  constexpr int TRI = NB * (NB + 1) / 2;
  __shared__ u16 lds[256 * 64];

  const int tid  = threadIdx.x;
  const int lane = tid & 63;
  const int w    = tid >> 6;
  const int wr   = w >> 1, wc = w & 1;

  const int nwg = (int)gridDim.x;
  const int id  = blockIdx.x;
  const int swz = (id & 7) * (nwg >> 3) + (id >> 3);
  const int z   = swz / TRI;
  int rem = swz % TRI;
  int bm = 0;
  while (rem >= NB - bm) { rem -= NB - bm; ++bm; }
  const int bn = bm + rem;

  const u16* Qz = Q + (long)z * sQz;

  const int lrow = lane & 15;
  const int rx   = lane & 7;
  const int srow = lane >> 3;
  const int scol = ((lane & 7) ^ srow) << 3;

  const u16* srcs[8];
#pragma unroll
  for (int c = 0; c < 8; ++c) {
    int row = (w * 8 + c) * 8 + srow;
    srcs[c] = (row < 128)
        ? Qz + (long)(bm * 128 + row) * ldq + scol
        : Qz + (long)(bn * 128 + (row - 128)) * ldq + scol;
  }

  const u16* Alds = lds;
  const u16* Blds = lds + 128 * 64;

  f32x4 acc[4][4] = {};

  const int nk = K >> 6;
  for (int kt = 0; kt < nk; ++kt) {
#pragma unroll
    for (int c = 0; c < 8; ++c) {
      __builtin_amdgcn_global_load_lds(
          (const __attribute__((address_space(1))) uint32_t*)(srcs[c] + kt * 64),
          (__attribute__((address_space(3))) uint32_t*)(&lds[(w * 8 + c) * 512]),
          16, 0, 0);
    }
    __syncthreads();

#pragma unroll
    for (int ks = 0; ks < 2; ++ks) {
      const int sl = ((ks * 4 + (lane >> 4)) ^ rx) << 3;
      bf16x8 af[4], bfr[4];
#pragma unroll
      for (int t = 0; t < 4; ++t) {
        af[t]  = *(const bf16x8*)&Alds[(wr * 64 + t * 16 + lrow) * 64 + sl];
        bfr[t] = *(const bf16x8*)&Blds[(wc * 64 + t * 16 + lrow) * 64 + sl];
      }
#pragma unroll
      for (int mt = 0; mt < 4; ++mt)
#pragma unroll
        for (int nt = 0; nt < 4; ++nt)
          acc[mt][nt] = __builtin_amdgcn_mfma_f32_16x16x32_bf16(af[mt], bfr[nt], acc[mt][nt], 0, 0, 0);
    }
    __syncthreads();
  }

  u16* Pz = P + (long)z * sPz;
  const int rsub = (lane >> 4) << 2;
  const bool offdiag = (bn != bm);

#pragma unroll
  for (int mt = 0; mt < 4; ++mt)
#pragma unroll
    for (int nt = 0; nt < 4; ++nt) {
      const int row = bm * 128 + wr * 64 + mt * 16 + rsub;   // +r
      const int col = bn * 128 + wc * 64 + nt * 16 + lrow;
      u16 b0 = bf(sigmoid_s(acc[mt][nt][0]));
      u16 b1 = bf(sigmoid_s(acc[mt][nt][1]));
      u16 b2 = bf(sigmoid_s(acc[mt][nt][2]));
      u16 b3 = bf(sigmoid_s(acc[mt][nt][3]));
      Pz[(long)(row + 0) * ldp + col] = b0;
      Pz[(long)(row + 1) * ldp + col] = b1;
      Pz[(long)(row + 2) * ldp + col] = b2;
      Pz[(long)(row + 3) * ldp + col] = b3;
      if (offdiag) {
        ushort4 pk = make_ushort4(b0, b1, b2, b3);           // 4 consecutive cols of P^T row
        *(ushort4*)&Pz[(long)col * ldp + row] = pk;          // row%4==0 -> 8B aligned
      }
    }
}

// ---------------- launch ----------------
extern "C" void kernel_launch(void* const* d_in, const int* in_sizes, int n_in,
                              void* d_out, int out_size, void* d_ws, size_t ws_size,
                              hipStream_t stream) {
  const float* x  = (const float*)d_in[0];   // [4,4096,512]
  const float* Wq = (const float*)d_in[1];   // [512,512]
  const float* bq = (const float*)d_in[2];   // [512]
  const float* Wv = (const float*)d_in[3];   // [512,512]
  const float* bv = (const float*)d_in[4];   // [512]
  float* out = (float*)d_out;                // [4,4096,512] f32

  // workspace carve (all bf16)
  u16* xb  = (u16*)d_ws;                       // [16384][512]
  u16* qb  = xb  + (size_t)16384 * 512;        // [16384][512]
  u16* vT  = qb  + (size_t)16384 * 512;        // [512][16384]  (v transposed; batch col slices)
  u16* wqb = vT  + (size_t)512 * 16384;        // [512][512]
  u16* wvb = wqb + (size_t)512 * 512;          // [512][512]
  u16* P   = wvb + (size_t)512 * 512;          // [4 or 2][4096][4096] bf16

  const size_t base_elems = (size_t)16384 * 512 * 3 + (size_t)512 * 512 * 2;
  const size_t need_all4  = (base_elems + (size_t)4 * 4096 * 4096) * sizeof(u16);
  const bool all4 = ws_size >= need_all4;

  conv_kernel<<<8704, 256, 0, stream>>>(x, Wq, Wv, xb, wqb, wvb);

  // q[n][e] = sum_d xb[n][d]*Wq[e][d] + bq[e]   (bias per col)
  gemm_nt<0, 128, 128, 4, 128><<<512, 256, 0, stream>>>(xb, 512, 0, wqb, 512, 0,
                                                        qb, 512, 0, bq, 512);
  // vT[e][n] = sum_d Wv[e][d]*xb[n][d] + bv[e]  (bias per row)
  gemm_nt<1, 128, 128, 128, 4><<<512, 256, 0, stream>>>(wvb, 512, 0, xb, 512, 0,
                                                        vT, 16384, 0, bv, 512);

  if (all4) {
    // P = sigmoid(q q^T / sqrt(512)), symmetric: 528 tiles/batch, both halves stored
    gemm_sym_sig<32><<<4 * 528, 256, 0, stream>>>(qb, 512, (long)4096 * 512,
                                                  P, 4096, (long)4096 * 4096, 512);
    // O[n][d] = sum_m P[n][m] * v[m][d]; 128x128 tile, 512 blocks = 2/CU
    gemm_nt<3, 128, 128, 4, 32><<<512, 256, 0, stream>>>(
        P, 4096, (long)4096 * 4096, vT, 16384, (long)4096,
        out, 512, (long)4096 * 512, nullptr, 4096);
  } else {
    for (int p = 0; p < 2; ++p) {
      const u16* qbp = qb + (size_t)p * 2 * 4096 * 512;
      gemm_sym_sig<32><<<2 * 528, 256, 0, stream>>>(qbp, 512, (long)4096 * 512,
                                                    P, 4096, (long)4096 * 4096, 512);
      gemm_nt<3, 64, 128, 4, 64><<<512, 256, 0, stream>>>(
          P, 4096, (long)4096 * 4096, vT + (size_t)p * 2 * 4096, 16384, (long)4096,
          out + (size_t)p * 2 * 4096 * 512, 512, (long)4096 * 512, nullptr, 4096);
    }
  }
}

// Round 5
// 169.984 us; speedup vs baseline: 1.8152x; 1.0833x over previous
//
#include <hip/hip_runtime.h>
#include <hip/hip_bf16.h>
#include <stdint.h>

#define DEV __device__ __forceinline__

typedef unsigned short u16;
typedef __attribute__((ext_vector_type(8))) short bf16x8;   // 8 bf16 (4 VGPRs) MFMA A/B frag
typedef __attribute__((ext_vector_type(4))) float f32x4;    // MFMA C/D frag

DEV u16 bf(float v) {
  __hip_bfloat16 h = __float2bfloat16(v);
  union { __hip_bfloat16 h; u16 u; } x; x.h = h;
  return x.u;
}

// sigmoid(v/sqrt(512)) = 1/(1+exp2(v * -log2(e)/sqrt(512)))
DEV float sigmoid_s(float v) {
  float e = __builtin_amdgcn_exp2f(v * -0.0637587143f);
  return __builtin_amdgcn_rcpf(1.0f + e);
}

// ---------------- f32 -> bf16 conversion (x, Wq, Wv) ----------------
__global__ void conv_kernel(const float* __restrict__ x,
                            const float* __restrict__ Wq,
                            const float* __restrict__ Wv,
                            u16* __restrict__ xb,
                            u16* __restrict__ wqb,
                            u16* __restrict__ wvb) {
  const int NX4 = (16384 * 512) / 4;
  const int NW4 = (512 * 512) / 4;
  int i = blockIdx.x * blockDim.x + threadIdx.x;
  const float4* src; u16* dst; int off;
  if (i < NX4)            { src = (const float4*)x;  dst = xb;  off = i; }
  else if (i < NX4 + NW4) { src = (const float4*)Wq; dst = wqb; off = i - NX4; }
  else                    { src = (const float4*)Wv; dst = wvb; off = i - NX4 - NW4; }
  float4 f = src[off];
  ushort4 o = make_ushort4(bf(f.x), bf(f.y), bf(f.z), bf(f.w));
  ((ushort4*)dst)[off] = o;
}

// ---------------- generic BMxBNxBK NT GEMM, bf16 in, MFMA ----------------
// C[m][n] = sum_k A[m][k] * B[n][k]  (both row-major with K inner = NT)
// Flat grid; XCD-chunked bijective swizzle (T1, m204), bn-fastest decode.
// LDS XOR-swizzle (T2): linear global_load_lds dest; source 8-elem slot
// pre-XORed with (row&7); frag read applies the same involution (rule #21).
// EPI: 0 = +bias[col] -> bf16 | 1 = +bias[row] -> bf16 | 3 = f32 out
template <int EPI, int BM, int BN, int BK, int NBN, int NBM>
__global__ __launch_bounds__(256, 2)
void gemm_nt(const u16* __restrict__ A, int lda, long sAz,
             const u16* __restrict__ B, int ldb, long sBz,
             void* __restrict__ Cv, int ldc, long sCz,
             const float* __restrict__ bias, int K) {
  constexpr int MREP = BM / 32;
  constexpr int NREP = BN / 32;
  constexpr int SPR  = BK / 8;               // 8-u16 slots per row
  constexpr int RPC  = 512 / BK;             // rows per 1KB staging chunk
  constexpr int CPW  = (BM + BN) / RPC / 4;  // chunks per wave per K-step
  __shared__ u16 lds[(BM + BN) * BK];

  const int tid  = threadIdx.x;
  const int lane = tid & 63;
  const int w    = tid >> 6;        // wave 0..3
  const int wr   = w >> 1, wc = w & 1;

  const int nwg = (int)gridDim.x;   // divisible by 8
  const int id  = blockIdx.x;
  const int swz = (id & 7) * (nwg >> 3) + (id >> 3);
  const int bn  = swz % NBN;
  const int t0  = swz / NBN;
  const int bm  = t0 % NBM;
  const int z   = t0 / NBM;

  A += (long)z * sAz;
  B += (long)z * sBz;

  const int lrow = lane & 15;           // frag row (A) / col (B)
  const int rx   = lane & 7;            // read-side swizzle key (lrow & 7)

  const int srow  = lane / SPR;         // row within staging chunk
  const int slot0 = lane % SPR;         // 8-u16 slot within row

  const u16* srcs[CPW];
#pragma unroll
  for (int c = 0; c < CPW; ++c) {
    int row  = (w * CPW + c) * RPC + srow;       // row within [A-tile | B-tile]
    int scol = ((slot0 ^ (row & 7)) & (SPR - 1)) * 8;  // pre-swizzled source slot
    srcs[c] = (row < BM)
        ? A + (long)(bm * BM + row) * lda + scol
        : B + (long)(bn * BN + (row - BM)) * ldb + scol;
  }

  const u16* Alds = lds;
  const u16* Blds = lds + BM * BK;

  f32x4 acc[MREP][NREP] = {};

  const int nk = K / BK;
  for (int kt = 0; kt < nk; ++kt) {
#pragma unroll
    for (int c = 0; c < CPW; ++c) {
      __builtin_amdgcn_global_load_lds(
          (const __attribute__((address_space(1))) uint32_t*)(srcs[c] + kt * BK),
          (__attribute__((address_space(3))) uint32_t*)(&lds[(w * CPW + c) * 512]),
          16, 0, 0);
    }
    __syncthreads();

#pragma unroll
    for (int ks = 0; ks < BK / 32; ++ks) {
      const int sl = (((ks * 4 + (lane >> 4)) ^ rx) & (SPR - 1)) * 8;
      bf16x8 af[MREP], bfr[NREP];
#pragma unroll
      for (int t = 0; t < MREP; ++t)
        af[t]  = *(const bf16x8*)&Alds[(wr * (BM / 2) + t * 16 + lrow) * BK + sl];
#pragma unroll
      for (int t = 0; t < NREP; ++t)
        bfr[t] = *(const bf16x8*)&Blds[(wc * (BN / 2) + t * 16 + lrow) * BK + sl];
#pragma unroll
      for (int mt = 0; mt < MREP; ++mt)
#pragma unroll
        for (int nt = 0; nt < NREP; ++nt)
          acc[mt][nt] = __builtin_amdgcn_mfma_f32_16x16x32_bf16(af[mt], bfr[nt], acc[mt][nt], 0, 0, 0);
    }
    __syncthreads();
  }

  // epilogue: C/D layout col = lane&15, row = (lane>>4)*4 + r  [verified m89/m91]
  const int row0 = bm * BM + wr * (BM / 2);
  const int col0 = bn * BN + wc * (BN / 2);
  const int rsub = (lane >> 4) << 2;

  if (EPI == 3) {
    float* C = (float*)Cv + (long)z * sCz;
#pragma unroll
    for (int mt = 0; mt < MREP; ++mt)
#pragma unroll
      for (int nt = 0; nt < NREP; ++nt)
#pragma unroll
        for (int r = 0; r < 4; ++r)
          C[(long)(row0 + mt * 16 + rsub + r) * ldc + col0 + nt * 16 + lrow] = acc[mt][nt][r];
  } else {
    u16* C = (u16*)Cv + (long)z * sCz;
#pragma unroll
    for (int mt = 0; mt < MREP; ++mt)
#pragma unroll
      for (int nt = 0; nt < NREP; ++nt)
#pragma unroll
        for (int r = 0; r < 4; ++r) {
          int row = row0 + mt * 16 + rsub + r;
          int col = col0 + nt * 16 + lrow;
          float v = acc[mt][nt][r];
          if (EPI == 0) v += bias[col];
          if (EPI == 1) v += bias[row];
          C[(long)row * ldc + col] = bf(v);
        }
  }
}

// ---------------- symmetric sigmoid(QQ^T) GEMM: only bn>=bm tiles ----------------
// Grid = Z * 528 flat (XCD-swizzled). Off-diagonal blocks store both the
// normal and the transposed tile; BOTH go through a padded-LDS bounce so
// every global store is a dense 256B row segment (was 32B scatter).
template <int NB>   // tiles per dim; BM=BN=128; TRI = NB*(NB+1)/2
__global__ __launch_bounds__(256, 2)
void gemm_sym_sig(const u16* __restrict__ Q, int ldq, long sQz,
                  u16* __restrict__ P, int ldp, long sPz, int K) {
  constexpr int TRI = NB * (NB + 1) / 2;
  constexpr int LSTR = 136;                  // u16 row stride: 16B-aligned, bank-spread
  __shared__ u16 lds[128 * LSTR];            // staging (256*64=16384) | bounce (128*136)

  const int tid  = threadIdx.x;
  const int lane = tid & 63;
  const int w    = tid >> 6;
  const int wr   = w >> 1, wc = w & 1;

  const int nwg = (int)gridDim.x;
  const int id  = blockIdx.x;
  const int swz = (id & 7) * (nwg >> 3) + (id >> 3);
  const int z   = swz / TRI;
  int rem = swz % TRI;
  int bm = 0;
  while (rem >= NB - bm) { rem -= NB - bm; ++bm; }
  const int bn = bm + rem;

  const u16* Qz = Q + (long)z * sQz;

  const int lrow = lane & 15;
  const int rx   = lane & 7;
  const int srow = lane >> 3;
  const int scol = ((lane & 7) ^ srow) << 3;

  const u16* srcs[8];
#pragma unroll
  for (int c = 0; c < 8; ++c) {
    int row = (w * 8 + c) * 8 + srow;
    srcs[c] = (row < 128)
        ? Qz + (long)(bm * 128 + row) * ldq + scol
        : Qz + (long)(bn * 128 + (row - 128)) * ldq + scol;
  }

  const u16* Alds = lds;
  const u16* Blds = lds + 128 * 64;

  f32x4 acc[4][4] = {};

  const int nk = K >> 6;
  for (int kt = 0; kt < nk; ++kt) {
#pragma unroll
    for (int c = 0; c < 8; ++c) {
      __builtin_amdgcn_global_load_lds(
          (const __attribute__((address_space(1))) uint32_t*)(srcs[c] + kt * 64),
          (__attribute__((address_space(3))) uint32_t*)(&lds[(w * 8 + c) * 512]),
          16, 0, 0);
    }
    __syncthreads();

#pragma unroll
    for (int ks = 0; ks < 2; ++ks) {
      const int sl = ((ks * 4 + (lane >> 4)) ^ rx) << 3;
      bf16x8 af[4], bfr[4];
#pragma unroll
      for (int t = 0; t < 4; ++t) {
        af[t]  = *(const bf16x8*)&Alds[(wr * 64 + t * 16 + lrow) * 64 + sl];
        bfr[t] = *(const bf16x8*)&Blds[(wc * 64 + t * 16 + lrow) * 64 + sl];
      }
#pragma unroll
      for (int mt = 0; mt < 4; ++mt)
#pragma unroll
        for (int nt = 0; nt < 4; ++nt)
          acc[mt][nt] = __builtin_amdgcn_mfma_f32_16x16x32_bf16(af[mt], bfr[nt], acc[mt][nt], 0, 0, 0);
    }
    __syncthreads();
  }

  u16* Pz = P + (long)z * sPz;
  const int rsub = (lane >> 4) << 2;
  const bool offdiag = (bn != bm);

  // sigmoid all 64 outputs once
  u16 sb[4][4][4];
#pragma unroll
  for (int mt = 0; mt < 4; ++mt)
#pragma unroll
    for (int nt = 0; nt < 4; ++nt)
#pragma unroll
      for (int r = 0; r < 4; ++r)
        sb[mt][nt][r] = bf(sigmoid_s(acc[mt][nt][r]));

  const int rl = wr * 64 + rsub;   // local row base (+mt*16, +r)
  const int cl = wc * 64 + lrow;   // local col base (+nt*16)
  const int coloff = (lane & 15) * 8;

  // pass 1: normal orientation bounce -> coalesced 256B row stores
#pragma unroll
  for (int mt = 0; mt < 4; ++mt)
#pragma unroll
    for (int nt = 0; nt < 4; ++nt)
#pragma unroll
      for (int r = 0; r < 4; ++r)
        lds[(rl + mt * 16 + r) * LSTR + cl + nt * 16] = sb[mt][nt][r];
  __syncthreads();
#pragma unroll
  for (int j = 0; j < 8; ++j) {
    int row = j * 16 + w * 4 + (lane >> 4);
    bf16x8 v = *(const bf16x8*)&lds[row * LSTR + coloff];
    *(bf16x8*)&Pz[(long)(bm * 128 + row) * ldp + bn * 128 + coloff] = v;
  }

  if (offdiag) {
    __syncthreads();   // WAR: pass-1 reads done before overwrite
    // pass 2: transposed orientation; frag's 4 rows = 4 consecutive u16 -> uint2
#pragma unroll
    for (int mt = 0; mt < 4; ++mt)
#pragma unroll
      for (int nt = 0; nt < 4; ++nt) {
        uint2 pk;
        pk.x = (uint32_t)sb[mt][nt][0] | ((uint32_t)sb[mt][nt][1] << 16);
        pk.y = (uint32_t)sb[mt][nt][2] | ((uint32_t)sb[mt][nt][3] << 16);
        *(uint2*)&lds[(cl + nt * 16) * LSTR + rl + mt * 16] = pk;
      }
    __syncthreads();
#pragma unroll
    for (int j = 0; j < 8; ++j) {
      int row = j * 16 + w * 4 + (lane >> 4);
      bf16x8 v = *(const bf16x8*)&lds[row * LSTR + coloff];
      *(bf16x8*)&Pz[(long)(bn * 128 + row) * ldp + bm * 128 + coloff] = v;
    }
  }
}

// ---------------- launch ----------------
extern "C" void kernel_launch(void* const* d_in, const int* in_sizes, int n_in,
                              void* d_out, int out_size, void* d_ws, size_t ws_size,
                              hipStream_t stream) {
  const float* x  = (const float*)d_in[0];   // [4,4096,512]
  const float* Wq = (const float*)d_in[1];   // [512,512]
  const float* bq = (const float*)d_in[2];   // [512]
  const float* Wv = (const float*)d_in[3];   // [512,512]
  const float* bv = (const float*)d_in[4];   // [512]
  float* out = (float*)d_out;                // [4,4096,512] f32

  // workspace carve (all bf16)
  u16* xb  = (u16*)d_ws;                       // [16384][512]
  u16* qb  = xb  + (size_t)16384 * 512;        // [16384][512]
  u16* vT  = qb  + (size_t)16384 * 512;        // [512][16384]  (v transposed; batch col slices)
  u16* wqb = vT  + (size_t)512 * 16384;        // [512][512]
  u16* wvb = wqb + (size_t)512 * 512;          // [512][512]
  u16* P   = wvb + (size_t)512 * 512;          // [4 or 2][4096][4096] bf16

  const size_t base_elems = (size_t)16384 * 512 * 3 + (size_t)512 * 512 * 2;
  const size_t need_all4  = (base_elems + (size_t)4 * 4096 * 4096) * sizeof(u16);
  const bool all4 = ws_size >= need_all4;

  conv_kernel<<<8704, 256, 0, stream>>>(x, Wq, Wv, xb, wqb, wvb);

  // q[n][e] = sum_d xb[n][d]*Wq[e][d] + bq[e]   (bias per col)
  gemm_nt<0, 128, 128, 64, 4, 128><<<512, 256, 0, stream>>>(xb, 512, 0, wqb, 512, 0,
                                                            qb, 512, 0, bq, 512);
  // vT[e][n] = sum_d Wv[e][d]*xb[n][d] + bv[e]  (bias per row)
  gemm_nt<1, 128, 128, 64, 128, 4><<<512, 256, 0, stream>>>(wvb, 512, 0, xb, 512, 0,
                                                            vT, 16384, 0, bv, 512);

  if (all4) {
    // P = sigmoid(q q^T / sqrt(512)), symmetric: 528 tiles/batch, both halves stored
    gemm_sym_sig<32><<<4 * 528, 256, 0, stream>>>(qb, 512, (long)4096 * 512,
                                                  P, 4096, (long)4096 * 4096, 512);
    // O[n][d] = sum_m P[n][m] * v[m][d]; 128x128 tile, BK=128 (half the barriers)
    gemm_nt<3, 128, 128, 128, 4, 32><<<512, 256, 0, stream>>>(
        P, 4096, (long)4096 * 4096, vT, 16384, (long)4096,
        out, 512, (long)4096 * 512, nullptr, 4096);
  } else {
    for (int p = 0; p < 2; ++p) {
      const u16* qbp = qb + (size_t)p * 2 * 4096 * 512;
      gemm_sym_sig<32><<<2 * 528, 256, 0, stream>>>(qbp, 512, (long)4096 * 512,
                                                    P, 4096, (long)4096 * 4096, 512);
      gemm_nt<3, 64, 128, 128, 4, 64><<<512, 256, 0, stream>>>(
          P, 4096, (long)4096 * 4096, vT + (size_t)p * 2 * 4096, 16384, (long)4096,
          out + (size_t)p * 2 * 4096 * 512, 512, (long)4096 * 512, nullptr, 4096);
    }
  }
}